// Round 1
// 85.729 us; speedup vs baseline: 1.0091x; 1.0091x over previous
//
#include <hip/hip_runtime.h>
#include <math.h>

// Problem constants (fixed by reference setup_inputs):
// support: (B, N, K, D) fp32, query: (B, Q, D) fp32
// out = concat(agg (B,N,D), qgw (B,N,K,1)) fp32
constexpr int B = 4;
constexpr int N = 10;
constexpr int K = 5;
constexpr int Q = 512;
constexpr int D = 1536;  // 2 * 768

constexpr int QCH = 8;   // Q / 64 query chunks
constexpr int DCH = 6;   // D / 256 d chunks

// Workspace layout (floats) — every word read by agg_kernel is written by
// qstats_kernel first (no atomics, no zero-init, re-poison safe):
// [0, QCH*B*D)              : per-q-chunk column-sum partials  part[c][b][d]
// [CS_OFF, CS_OFF+B*QCH*DCH): per-block sum-of-squares partials cs[b][c][y]
constexpr int PART_OFF = 0;
constexpr int CS_OFF   = QCH * B * D;

// Kernel 1: per (q-chunk, d-chunk, b) block — column sums + sum of squares.
// grid = (QCH, DCH, B) = 192 blocks, block = 256. Thread handles one d, 64 q.
__global__ __launch_bounds__(256) void qstats_kernel(
    const float* __restrict__ query, float* __restrict__ ws) {
    const int tid = threadIdx.x;
    const int c   = blockIdx.x;           // q-chunk
    const int y   = blockIdx.y;           // d-chunk
    const int b   = blockIdx.z;
    const int d   = y * 256 + tid;

    const float* qp = query + (size_t)b * Q * D + (size_t)(c * 64) * D + d;
    float acc = 0.f, ssq = 0.f;
#pragma unroll 8
    for (int q = 0; q < 64; ++q) {
        float v = qp[(size_t)q * D];
        acc += v;
        ssq = fmaf(v, v, ssq);
    }
    // deterministic partial store — no atomic, no init required
    ws[PART_OFF + ((size_t)c * B + b) * D + d] = acc;

    // block-reduce ssq: wave64 shuffle then cross-wave via LDS
    for (int off = 32; off > 0; off >>= 1) ssq += __shfl_down(ssq, off);
    __shared__ float red[4];
    const int wave = tid >> 6, lane = tid & 63;
    if (lane == 0) red[wave] = ssq;
    __syncthreads();
    if (tid == 0) {
        ws[CS_OFF + (b * QCH + c) * DCH + y] = red[0] + red[1] + red[2] + red[3];
    }
}

// Kernel 2: per (b,n) block — reduce qbar partials into LDS, dot products,
// tanh, softmax over K, write qgw, weighted shot-aggregation.
// grid = B*N = 40, block = 256.
__global__ __launch_bounds__(256) void agg_kernel(
    const float* __restrict__ support, const float* __restrict__ ws,
    float* __restrict__ out) {
    const int tid = threadIdx.x;
    const int bn  = blockIdx.x;      // 0..B*N-1
    const int b   = bn / N;

    const float* sup = support + (size_t)bn * K * D;

    __shared__ float s_qbar[D];      // 6 KB
    __shared__ float s_red[2][K][4];
    __shared__ float s_w[K + 1];     // s_w[K] holds cb = mean ||q||^2

    // reduce the 8 per-q-chunk column-sum partials into LDS qbar
    for (int d = tid; d < D; d += 256) {
        float s = 0.f;
#pragma unroll
        for (int c = 0; c < QCH; ++c)
            s += ws[PART_OFF + ((size_t)c * B + b) * D + d];
        s_qbar[d] = s;
    }
    // reduce the 48 ||q||^2 partials (first wave only)
    if (tid < 64) {
        float v = (tid < QCH * DCH) ? ws[CS_OFF + b * (QCH * DCH) + tid] : 0.f;
        for (int off = 32; off > 0; off >>= 1) v += __shfl_down(v, off);
        if (tid == 0) s_w[K] = v * (1.f / Q);
    }
    __syncthreads();

    const int wave = tid >> 6, lane = tid & 63;
    for (int k = 0; k < K; ++k) {
        float a = 0.f, cdot = 0.f;
        for (int d = tid; d < D; d += 256) {
            float s = sup[k * D + d];
            a    = fmaf(s, s, a);
            cdot = fmaf(s, s_qbar[d], cdot);
        }
        for (int off = 32; off > 0; off >>= 1) {
            a    += __shfl_down(a, off);
            cdot += __shfl_down(cdot, off);
        }
        if (lane == 0) { s_red[0][k][wave] = a; s_red[1][k][wave] = cdot; }
    }
    __syncthreads();

    if (tid < K) {
        const int k = tid;
        float ssk = s_red[0][k][0] + s_red[0][k][1] + s_red[0][k][2] + s_red[0][k][3];
        float sqk = s_red[1][k][0] + s_red[1][k][1] + s_red[1][k][2] + s_red[1][k][3];
        // mean_q dist_sq = -||S||^2 + 2*S.qbar_mean - mean||q||^2
        float m = -ssk + 2.f * sqk * (1.f / Q) - s_w[K];
        s_w[k] = tanhf(m);
    }
    __syncthreads();
    if (tid == 0) {
        float mx = s_w[0];
        for (int k = 1; k < K; ++k) mx = fmaxf(mx, s_w[k]);
        float e[K], sum = 0.f;
        for (int k = 0; k < K; ++k) { e[k] = expf(s_w[k] - mx); sum += e[k]; }
        float inv = 1.f / sum;
        for (int k = 0; k < K; ++k) s_w[k] = e[k] * inv;
    }
    __syncthreads();

    // qgw output (after agg block: B*N*D floats)
    if (tid < K) out[(size_t)B * N * D + bn * K + tid] = s_w[tid];

    float w[K];
#pragma unroll
    for (int k = 0; k < K; ++k) w[k] = s_w[k];

    for (int d = tid; d < D; d += 256) {
        float acc = 0.f;
#pragma unroll
        for (int k = 0; k < K; ++k) acc = fmaf(sup[k * D + d], w[k], acc);
        out[(size_t)bn * D + d] = acc;
    }
}

extern "C" void kernel_launch(void* const* d_in, const int* in_sizes, int n_in,
                              void* d_out, int out_size, void* d_ws, size_t ws_size,
                              hipStream_t stream) {
    const float* support = (const float*)d_in[0];
    const float* query   = (const float*)d_in[1];
    float* out = (float*)d_out;
    float* ws  = (float*)d_ws;

    dim3 g1(QCH, DCH, B);   // 192 blocks
    qstats_kernel<<<g1, 256, 0, stream>>>(query, ws);

    agg_kernel<<<B * N, 256, 0, stream>>>(support, ws, out);
}